// Round 1
// baseline (1122.456 us; speedup 1.0000x reference)
//
#include <hip/hip_runtime.h>
#include <math.h>

#define PI2 6.283185307179586f

// Problem constants
// B=32, H=128, W=128, C=128, hm modes=32 (rows 0..15 and 112..127), k modes=17
// Layouts (float2 = complex):
//  kout0/kin0: [32][128][2][64]  (hm, i/j, d, r)
//  kout1/kin1: [17][128][2][64]
//  S0: [32][128][128][2] (hm,i,j,d)   S1: [17][128][128][2]
//  K:  [544][128][128]   (m=hm*17+k, i, j)
//  Xw: [32][128][17][128] (b,y,k,c)   Q: same (b,y,k,o)
//  Xf: [32][32][17][128]  (b,hm,k,c)  Y: same (b,hm,k,i)

// ---------------- S0/S1 build: S[s,i,j,d] = sum_r ko[s,i,d,r]*ki[s,j,d,r] ----
__global__ __launch_bounds__(128) void k_S(
    const float2* __restrict__ ko0, const float2* __restrict__ ki0,
    const float2* __restrict__ ko1, const float2* __restrict__ ki1,
    float2* __restrict__ S0, float2* __restrict__ S1) {
  int bid = blockIdx.x;
  int s = bid >> 7;      // 0..48
  int i = bid & 127;
  int j = threadIdx.x;   // 128 threads
  const float2* ko; const float2* ki; float2* S; int si;
  if (s < 32) { ko = ko0; ki = ki0; S = S0; si = s; }
  else        { ko = ko1; ki = ki1; S = S1; si = s - 32; }
  __shared__ float2 koS[2][64];
  // row (si,i): 128 float2 laid out as d*64+r
  koS[j >> 6][j & 63] = ko[(si * 128 + i) * 128 + j];
  __syncthreads();
  const float2* kirow = ki + (si * 128 + j) * 128;
  float2 acc[2];
#pragma unroll
  for (int d = 0; d < 2; d++) {
    float2 a2 = make_float2(0.f, 0.f);
    for (int r = 0; r < 64; r++) {
      float2 a = koS[d][r];
      float2 b = kirow[d * 64 + r];
      a2.x += a.x * b.x - a.y * b.y;
      a2.y += a.x * b.y + a.y * b.x;
    }
    acc[d] = a2;
  }
  ((float4*)S)[(si * 128 + i) * 128 + j] =
      make_float4(acc[0].x, acc[0].y, acc[1].x, acc[1].y);
}

// ---------------- K build: K[m,i,j] = sum_d S0[hm,i,j,d]*S1[k,i,j,d] --------
__global__ __launch_bounds__(256) void k_K(
    const float2* __restrict__ S0, const float2* __restrict__ S1,
    float2* __restrict__ K) {
  int tid = blockIdx.x * 256 + threadIdx.x;
  if (tid >= 544 * 16384) return;
  int m = tid >> 14;
  int ij = tid & 16383;
  int hm = m / 17, w = m - hm * 17;
  float4 a = ((const float4*)S0)[hm * 16384 + ij];
  float4 b = ((const float4*)S1)[w * 16384 + ij];
  float2 acc;
  acc.x = a.x * b.x - a.y * b.y + a.z * b.z - a.w * b.w;
  acc.y = a.x * b.y + a.y * b.x + a.z * b.w + a.w * b.z;
  K[tid] = acc;
}

// ---------------- Forward stage 1 (W-axis truncated DFT, scaled) ------------
// Xw[b,y,k,c] = (1/16384) * sum_x X[b,y,x,c] e^{-2pi i k x/128}
__global__ __launch_bounds__(256) void k_F1(
    const float* __restrict__ X, float2* __restrict__ Xw) {
  __shared__ float2 tw[128];
  int t = threadIdx.x;
  if (t < 128) { float s, c; __sincosf(PI2 * t / 128.f, &s, &c); tw[t] = make_float2(c, s); }
  __syncthreads();
  int c = t & 127;
  int b = blockIdx.x >> 6;
  int y = (blockIdx.x & 63) * 2 + (t >> 7);
  const float* xrow = X + ((size_t)(b * 128 + y) * 128) * 128 + c;
  float2 acc[17];
#pragma unroll
  for (int k = 0; k < 17; k++) acc[k] = make_float2(0.f, 0.f);
  for (int x = 0; x < 128; x++) {
    float xv = xrow[x * 128];
#pragma unroll
    for (int k = 0; k < 17; k++) {
      float2 w = tw[(k * x) & 127];  // e^{-i th}: (cos, -sin)
      acc[k].x += xv * w.x;
      acc[k].y -= xv * w.y;
    }
  }
  const float sc = 1.f / 16384.f;
  float2* orow = Xw + ((size_t)(b * 128 + y) * 17) * 128 + c;
#pragma unroll
  for (int k = 0; k < 17; k++)
    orow[k * 128] = make_float2(acc[k].x * sc, acc[k].y * sc);
}

// ---------------- Forward stage 2 (H-axis truncated DFT) --------------------
// Xf[b,hm,k,c] = sum_y Xw[b,y,k,c] e^{-2pi i h(hm) y/128}
__global__ __launch_bounds__(256) void k_F2(
    const float2* __restrict__ Xw, float2* __restrict__ Xf) {
  __shared__ float2 tw[128];
  __shared__ float2 red[32 * 128];
  int t = threadIdx.x;
  if (t < 128) { float s, c; __sincosf(PI2 * t / 128.f, &s, &c); tw[t] = make_float2(c, s); }
  __syncthreads();
  int b = blockIdx.x / 17, k = blockIdx.x - b * 17;
  int c = t & 127, half = t >> 7;
  float2 acc[32];
#pragma unroll
  for (int hm = 0; hm < 32; hm++) acc[hm] = make_float2(0.f, 0.f);
  for (int yy = 0; yy < 64; yy++) {
    int y = half * 64 + yy;
    float2 xv = Xw[((size_t)(b * 128 + y) * 17 + k) * 128 + c];
#pragma unroll
    for (int hm = 0; hm < 32; hm++) {
      int h = hm < 16 ? hm : hm + 96;
      float2 w = tw[(h * y) & 127];
      // acc += xv * (cos, -sin)
      acc[hm].x += xv.x * w.x + xv.y * w.y;
      acc[hm].y += xv.y * w.x - xv.x * w.y;
    }
  }
  if (half == 1) {
#pragma unroll
    for (int hm = 0; hm < 32; hm++) red[hm * 128 + c] = acc[hm];
  }
  __syncthreads();
  if (half == 0) {
#pragma unroll
    for (int hm = 0; hm < 32; hm++) {
      float2 o = red[hm * 128 + c];
      o.x += acc[hm].x; o.y += acc[hm].y;
      Xf[((size_t)(b * 32 + hm) * 17 + k) * 128 + c] = o;
    }
  }
}

// ---------------- Spectral per-mode complex GEMM ----------------------------
// Y[b,m,i] = sum_j K[m,i,j] * Xf[b,m,j]   (m = hm*17+k fixed per block)
__global__ __launch_bounds__(256) void k_spec(
    const float2* __restrict__ K, const float2* __restrict__ Xf,
    float2* __restrict__ Y) {
  __shared__ float2 Xs[32][128];
  __shared__ float2 Ks[16][129];
  int m = blockIdx.x;
  int hm = m / 17, w = m - hm * 17;
  int t = threadIdx.x;
  for (int q = t; q < 32 * 128; q += 256) {
    int b = q >> 7, j = q & 127;
    Xs[b][j] = Xf[((size_t)(b * 32 + hm) * 17 + w) * 128 + j];
  }
  int i = t & 127, bh = t >> 7;
  float2 acc[16];
#pragma unroll
  for (int bb = 0; bb < 16; bb++) acc[bb] = make_float2(0.f, 0.f);
  const float2* Km = K + (size_t)m * 16384;
  for (int jt = 0; jt < 128; jt += 16) {
    __syncthreads();
    for (int q = t; q < 16 * 128; q += 256) {
      int ii = q >> 4, jj = q & 15;
      Ks[jj][ii] = Km[ii * 128 + jt + jj];
    }
    __syncthreads();
#pragma unroll 4
    for (int jj = 0; jj < 16; jj++) {
      float2 kv = Ks[jj][i];
#pragma unroll
      for (int bb = 0; bb < 16; bb++) {
        float2 xv = Xs[bh * 16 + bb][jt + jj];
        acc[bb].x += kv.x * xv.x - kv.y * xv.y;
        acc[bb].y += kv.x * xv.y + kv.y * xv.x;
      }
    }
  }
#pragma unroll
  for (int bb = 0; bb < 16; bb++) {
    int b = bh * 16 + bb;
    Y[((size_t)(b * 32 + hm) * 17 + w) * 128 + i] = acc[bb];
  }
}

// ---------------- Inverse stage 1 (H-axis expansion) ------------------------
// Q[b,y,k,o] = sum_hm Y[b,hm,k,o] e^{+2pi i h(hm) y/128}
__global__ __launch_bounds__(256) void k_I1(
    const float2* __restrict__ Y, float2* __restrict__ Q) {
  __shared__ float2 tw[128];
  __shared__ float2 Ys[32][128];
  int t = threadIdx.x;
  if (t < 128) { float s, c; __sincosf(PI2 * t / 128.f, &s, &c); tw[t] = make_float2(c, s); }
  int b = blockIdx.x / 17, k = blockIdx.x - b * 17;
  for (int q = t; q < 32 * 128; q += 256) {
    int hm = q >> 7, o = q & 127;
    Ys[hm][o] = Y[((size_t)(b * 32 + hm) * 17 + k) * 128 + o];
  }
  __syncthreads();
  int o = t & 127, yh = t >> 7;
  for (int yy = 0; yy < 64; yy++) {
    int y = yh * 64 + yy;
    float2 acc = make_float2(0.f, 0.f);
#pragma unroll
    for (int hm = 0; hm < 32; hm++) {
      int h = hm < 16 ? hm : hm + 96;
      float2 w = tw[(h * y) & 127];  // e^{+i th}
      float2 v = Ys[hm][o];
      acc.x += v.x * w.x - v.y * w.y;
      acc.y += v.x * w.y + v.y * w.x;
    }
    Q[((size_t)(b * 128 + y) * 17 + k) * 128 + o] = acc;
  }
}

// ---------------- Inverse stage 2 (W-axis real synthesis) -------------------
// out[b,y,x,o] = sum_k wk * Re(Q[b,y,k,o] e^{+2pi i k x/128}), w0=1 else 2
__global__ __launch_bounds__(256) void k_I2(
    const float2* __restrict__ Q, float* __restrict__ out) {
  __shared__ float2 tw[128];
  __shared__ float2 Qs[17][128];
  int t = threadIdx.x;
  if (t < 128) { float s, c; __sincosf(PI2 * t / 128.f, &s, &c); tw[t] = make_float2(c, s); }
  int b = blockIdx.x >> 7, y = blockIdx.x & 127;
  for (int q = t; q < 17 * 128; q += 256) {
    int k = q >> 7, o = q & 127;
    float2 v = Q[((size_t)(b * 128 + y) * 17 + k) * 128 + o];
    float wgt = (k == 0) ? 1.f : 2.f;
    Qs[k][o] = make_float2(v.x * wgt, v.y * wgt);
  }
  __syncthreads();
  int o = t & 127, xh = t >> 7;
  float* orow = out + ((size_t)(b * 128 + y) * 128) * 128 + o;
  for (int xx = 0; xx < 64; xx++) {
    int x = xh * 64 + xx;
    float acc = 0.f;
#pragma unroll
    for (int k = 0; k < 17; k++) {
      float2 w = tw[(k * x) & 127];
      float2 v = Qs[k][o];
      acc += v.x * w.x - v.y * w.y;  // Re(v * e^{+i th})
    }
    orow[x * 128] = acc;
  }
}

extern "C" void kernel_launch(void* const* d_in, const int* in_sizes, int n_in,
                              void* d_out, int out_size, void* d_ws, size_t ws_size,
                              hipStream_t stream) {
  (void)in_sizes; (void)n_in; (void)out_size;
  const float*  X     = (const float*)d_in[0];
  const float2* kout0 = (const float2*)d_in[1];
  const float2* kin0  = (const float2*)d_in[2];
  const float2* kout1 = (const float2*)d_in[3];
  const float2* kin1  = (const float2*)d_in[4];
  float* out = (float*)d_out;

  // Workspace layout (float2 units):
  //  A  : 8,912,896  (Xw, later reused as Q)
  //  K  : 8,912,896
  //  C  : 4,456,448  (S0+S1 first; then Xf + Y alias the same region)
  const size_t NA = 8912896;
  const size_t need = (2 * NA + 4456448) * sizeof(float2);  // ~170 MB
  if (ws_size < need) return;  // insufficient scratch -> visible validation fail
  float2* ws = (float2*)d_ws;
  float2* A  = ws;
  float2* K  = ws + NA;
  float2* C  = ws + 2 * NA;
  float2* S0 = C;               // 1,048,576
  float2* S1 = C + 1048576;     //   557,056
  float2* Xf = C;               // 2,228,224 (S0/S1 dead after k_K)
  float2* Yk = C + 2228224;     // 2,228,224

  k_S   <<<49 * 128, 128, 0, stream>>>(kout0, kin0, kout1, kin1, S0, S1);
  k_F1  <<<32 * 64, 256, 0, stream>>>(X, A);
  k_K   <<<(544 * 16384) / 256, 256, 0, stream>>>(S0, S1, K);
  k_F2  <<<32 * 17, 256, 0, stream>>>(A, Xf);      // after k_K (aliases S0/S1)
  k_spec<<<544, 256, 0, stream>>>(K, Xf, Yk);
  k_I1  <<<32 * 17, 256, 0, stream>>>(Yk, A);      // A now Q
  k_I2  <<<32 * 128, 256, 0, stream>>>(A, out);
}

// Round 2
// 1045.231 us; speedup vs baseline: 1.0739x; 1.0739x over previous
//
#include <hip/hip_runtime.h>
#include <math.h>

#define PI2 6.283185307179586f

// B=32, H=128, W=128, C=128; hm modes 32 (rows 0..15,112..127), k modes 17
// Layouts (float2 = complex):
//  kout0/kin0: [32][128][2][64]; kout1/kin1: [17][128][2][64]
//  S0: [32][128][128]{d0,d1} as float4   S1: [17][128][128] float4
//  Xw/Q: [32][128][17][128] f2   Xf/Y: [32][32][17][128] f2

// ---------------- S build: S[s,i,j,d] = sum_r ko[s,i,d,r]*ki[s,j,d,r] -------
__global__ __launch_bounds__(128) void k_S(
    const float2* __restrict__ ko0, const float2* __restrict__ ki0,
    const float2* __restrict__ ko1, const float2* __restrict__ ki1,
    float4* __restrict__ S0, float4* __restrict__ S1) {
  int bid = blockIdx.x;
  int s = bid >> 7;      // 0..48
  int i = bid & 127;
  int j = threadIdx.x;   // 128 threads
  const float2* ko; const float2* ki; float4* S; int si;
  if (s < 32) { ko = ko0; ki = ki0; S = S0; si = s; }
  else        { ko = ko1; ki = ki1; S = S1; si = s - 32; }
  __shared__ float2 koS[2][64];
  koS[j >> 6][j & 63] = ko[(si * 128 + i) * 128 + j];
  __syncthreads();
  const float2* kirow = ki + (si * 128 + j) * 128;
  float2 acc[2];
#pragma unroll
  for (int d = 0; d < 2; d++) {
    float2 a2 = make_float2(0.f, 0.f);
    for (int r = 0; r < 64; r++) {
      float2 a = koS[d][r];
      float2 b = kirow[d * 64 + r];
      a2.x += a.x * b.x - a.y * b.y;
      a2.y += a.x * b.y + a.y * b.x;
    }
    acc[d] = a2;
  }
  S[(si * 128 + i) * 128 + j] = make_float4(acc[0].x, acc[0].y, acc[1].x, acc[1].y);
}

// ---------------- F1: Xw[b,y,k,c] = sc * sum_x X[b,y,x,c] e^{-i 2pi kx/128} -
// 2 y-rows per block; half-block kg=0 does k=0..8, kg=1 does k=9..16.
__global__ __launch_bounds__(256) void k_F1(
    const float* __restrict__ X, float2* __restrict__ Xw) {
  __shared__ float2 tw[128];
  int t = threadIdx.x;
  if (t < 128) { float s, c; __sincosf(PI2 * t / 128.f, &s, &c); tw[t] = make_float2(c, s); }
  __syncthreads();
  const char* twc = (const char*)tw;
  int c = t & 127, kg = t >> 7;
  int b = blockIdx.x >> 6;
  int y0 = (blockIdx.x & 63) * 2;
  const float* xr0 = X + ((size_t)(b * 128 + y0) * 128) * 128 + c;
  const float* xr1 = xr0 + 16384;
  float2 a0[9], a1[9];
#pragma unroll
  for (int kk = 0; kk < 9; kk++) { a0[kk] = make_float2(0.f, 0.f); a1[kk] = make_float2(0.f, 0.f); }
  int kb8 = kg * 9 * 8;
  for (int x = 0; x < 128; x++) {
    float v0 = xr0[x * 128];
    float v1 = xr1[x * 128];
#pragma unroll
    for (int kk = 0; kk < 9; kk++) {
      int ob = ((kb8 + kk * 8) * x) & 1016;   // ((k*x)&127)*8
      float2 w = *(const float2*)(twc + ob);
      a0[kk].x += v0 * w.x; a0[kk].y -= v0 * w.y;
      a1[kk].x += v1 * w.x; a1[kk].y -= v1 * w.y;
    }
  }
  const float sc = 1.f / 16384.f;
  float2* o0 = Xw + ((size_t)(b * 128 + y0) * 17) * 128 + c;
#pragma unroll
  for (int kk = 0; kk < 9; kk++) {
    int k = kg * 9 + kk;
    if (k < 17) {
      o0[k * 128] = make_float2(a0[kk].x * sc, a0[kk].y * sc);
      o0[2176 + k * 128] = make_float2(a1[kk].x * sc, a1[kk].y * sc);
    }
  }
}

// ---------------- F2: Xf[b,hm,k,c] = sum_y Xw[b,y,k,c] e^{-i 2pi h y/128} ---
// half-block hh handles hm = hh*16 .. hh*16+15; each thread loops all 128 y.
__global__ __launch_bounds__(256) void k_F2(
    const float2* __restrict__ Xw, float2* __restrict__ Xf) {
  __shared__ float2 tw[128];
  int t = threadIdx.x;
  if (t < 128) { float s, c; __sincosf(PI2 * t / 128.f, &s, &c); tw[t] = make_float2(c, s); }
  __syncthreads();
  const char* twc = (const char*)tw;
  int b = blockIdx.x / 17, k = blockIdx.x - b * 17;
  int c = t & 127, hh = t >> 7;
  float2 acc[16];
#pragma unroll
  for (int q = 0; q < 16; q++) acc[q] = make_float2(0.f, 0.f);
  int hb8 = hh ? 112 * 8 : 0;  // h = hm (hm<16) or hm+96; hm = hh*16+q
  const float2* xp = Xw + ((size_t)(b * 128) * 17 + k) * 128 + c;
  for (int y = 0; y < 128; y++) {
    float2 xv = xp[(size_t)y * 2176];
#pragma unroll
    for (int q = 0; q < 16; q++) {
      int ob = ((hb8 + q * 8) * y) & 1016;
      float2 w = *(const float2*)(twc + ob);
      acc[q].x += xv.x * w.x + xv.y * w.y;
      acc[q].y += xv.y * w.x - xv.x * w.y;
    }
  }
  float2* op = Xf + ((size_t)(b * 32 + hh * 16) * 17 + k) * 128 + c;
#pragma unroll
  for (int q = 0; q < 16; q++) op[(size_t)q * 2176] = acc[q];
}

// ---------------- spec (fused K): Y[b,m,i] = sum_j K[m,i,j] Xf[b,m,j] -------
// K[m,i,j] = sum_d S0[hm,i,j,d]*S1[w,i,j,d], computed in the staging step.
__global__ __launch_bounds__(256) void k_spec(
    const float4* __restrict__ S0, const float4* __restrict__ S1,
    const float2* __restrict__ Xf, float2* __restrict__ Y) {
  __shared__ float2 Xs[32][128];
  __shared__ float2 Ks[16][129];
  int m = blockIdx.x;
  int hm = m / 17, w = m - hm * 17;
  int t = threadIdx.x;
  for (int q = t; q < 32 * 128; q += 256) {
    int b = q >> 7, j = q & 127;
    Xs[b][j] = Xf[((size_t)(b * 32 + hm) * 17 + w) * 128 + j];
  }
  const float4* s0p = S0 + (size_t)hm * 16384;
  const float4* s1p = S1 + (size_t)w * 16384;
  int i = t & 127, bh = t >> 7;
  float2 acc[16];
#pragma unroll
  for (int bb = 0; bb < 16; bb++) acc[bb] = make_float2(0.f, 0.f);
  for (int jt = 0; jt < 128; jt += 16) {
    __syncthreads();
    for (int q = t; q < 16 * 128; q += 256) {
      int ii = q >> 4, jj = q & 15;
      float4 a = s0p[ii * 128 + jt + jj];
      float4 b4 = s1p[ii * 128 + jt + jj];
      Ks[jj][ii] = make_float2(a.x * b4.x - a.y * b4.y + a.z * b4.z - a.w * b4.w,
                               a.x * b4.y + a.y * b4.x + a.z * b4.w + a.w * b4.z);
    }
    __syncthreads();
#pragma unroll 4
    for (int jj = 0; jj < 16; jj++) {
      float2 kv = Ks[jj][i];
#pragma unroll
      for (int bb = 0; bb < 16; bb++) {
        float2 xv = Xs[bh * 16 + bb][jt + jj];
        acc[bb].x += kv.x * xv.x - kv.y * xv.y;
        acc[bb].y += kv.x * xv.y + kv.y * xv.x;
      }
    }
  }
#pragma unroll
  for (int bb = 0; bb < 16; bb++) {
    int b = bh * 16 + bb;
    Y[((size_t)(b * 32 + hm) * 17 + w) * 128 + i] = acc[bb];
  }
}

// ---------------- I1: Q[b,y,k,o] = sum_hm Y[b,hm,k,o] e^{+i 2pi h y/128} ----
// Y values held in 32 complex registers per thread.
__global__ __launch_bounds__(256) void k_I1(
    const float2* __restrict__ Y, float2* __restrict__ Q) {
  __shared__ float2 tw[128];
  int t = threadIdx.x;
  if (t < 128) { float s, c; __sincosf(PI2 * t / 128.f, &s, &c); tw[t] = make_float2(c, s); }
  __syncthreads();
  const char* twc = (const char*)tw;
  int b = blockIdx.x / 17, k = blockIdx.x - b * 17;
  int o = t & 127, yh = t >> 7;
  float2 v[32];
#pragma unroll
  for (int hm = 0; hm < 32; hm++)
    v[hm] = Y[((size_t)(b * 32 + hm) * 17 + k) * 128 + o];
  float2* qp = Q + ((size_t)(b * 128) * 17 + k) * 128 + o;
  for (int yy = 0; yy < 64; yy++) {
    int y = yh * 64 + yy;
    float2 a = make_float2(0.f, 0.f);
#pragma unroll
    for (int hm = 0; hm < 32; hm++) {
      const int h8 = (hm < 16 ? hm : hm + 96) * 8;
      int ob = (h8 * y) & 1016;
      float2 w = *(const float2*)(twc + ob);
      a.x += v[hm].x * w.x - v[hm].y * w.y;
      a.y += v[hm].x * w.y + v[hm].y * w.x;
    }
    qp[(size_t)y * 2176] = a;
  }
}

// ---------------- I2: out[b,y,x,o] = sum_k wk Re(Q[b,y,k,o] e^{+i 2pi kx/128})
// 2 y-rows per block; Q held in 2x17 complex registers (weight folded in).
__global__ __launch_bounds__(256) void k_I2(
    const float2* __restrict__ Q, float* __restrict__ out) {
  __shared__ float2 tw[128];
  int t = threadIdx.x;
  if (t < 128) { float s, c; __sincosf(PI2 * t / 128.f, &s, &c); tw[t] = make_float2(c, s); }
  __syncthreads();
  const char* twc = (const char*)tw;
  int b = blockIdx.x >> 6;
  int y0 = (blockIdx.x & 63) * 2;
  int o = t & 127, xh = t >> 7;
  const float2* q0p = Q + ((size_t)(b * 128 + y0) * 17) * 128 + o;
  float2 q0[17], q1[17];
#pragma unroll
  for (int k = 0; k < 17; k++) {
    float wgt = (k == 0) ? 1.f : 2.f;
    float2 v0 = q0p[k * 128];
    float2 v1 = q0p[2176 + k * 128];
    q0[k] = make_float2(v0.x * wgt, v0.y * wgt);
    q1[k] = make_float2(v1.x * wgt, v1.y * wgt);
  }
  float* o0 = out + ((size_t)(b * 128 + y0) * 128) * 128 + o;
  float* o1 = o0 + 16384;
  for (int xx = 0; xx < 64; xx++) {
    int x = xh * 64 + xx;
    float s0 = 0.f, s1 = 0.f;
#pragma unroll
    for (int k = 0; k < 17; k++) {
      int ob = (k * 8 * x) & 1016;
      float2 w = *(const float2*)(twc + ob);
      s0 += q0[k].x * w.x - q0[k].y * w.y;
      s1 += q1[k].x * w.x - q1[k].y * w.y;
    }
    o0[x * 128] = s0;
    o1[x * 128] = s1;
  }
}

extern "C" void kernel_launch(void* const* d_in, const int* in_sizes, int n_in,
                              void* d_out, int out_size, void* d_ws, size_t ws_size,
                              hipStream_t stream) {
  (void)in_sizes; (void)n_in; (void)out_size;
  const float*  X     = (const float*)d_in[0];
  const float2* kout0 = (const float2*)d_in[1];
  const float2* kin0  = (const float2*)d_in[2];
  const float2* kout1 = (const float2*)d_in[3];
  const float2* kin1  = (const float2*)d_in[4];
  float* out = (float*)d_out;

  // Workspace (float2 units): A (Xw, reused as Q) | S0 | S1 | Xf | Y  = ~120 MB
  float2* ws = (float2*)d_ws;
  const size_t NA = 8912896;                 // 32*128*17*128
  float2* A  = ws;
  float2* S0 = ws + NA;                      // 1,048,576 f2 (as float4: 524,288)
  float2* S1 = S0 + 1048576;                 //   557,056 f2
  float2* Xf = S1 + 557056;                  // 2,228,224 f2
  float2* Yk = Xf + 2228224;                 // 2,228,224 f2
  const size_t need = (NA + 1048576 + 557056 + 2 * 2228224) * sizeof(float2);
  if (ws_size < need) return;

  k_S   <<<49 * 128, 128, 0, stream>>>(kout0, kin0, kout1, kin1,
                                       (float4*)S0, (float4*)S1);
  k_F1  <<<32 * 64, 256, 0, stream>>>(X, A);
  k_F2  <<<32 * 17, 256, 0, stream>>>(A, Xf);
  k_spec<<<544, 256, 0, stream>>>((const float4*)S0, (const float4*)S1, Xf, Yk);
  k_I1  <<<32 * 17, 256, 0, stream>>>(Yk, A);
  k_I2  <<<32 * 64, 256, 0, stream>>>(A, out);
}